// Round 1
// baseline (357.348 us; speedup 1.0000x reference)
//
#include <hip/hip_runtime.h>

#define Bc 2
#define Tc 2048
#define Cc 1024
#define Hc 16
#define Dc 64
#define Mtot (Bc*Tc)   // 4096
#define Kdim Cc        // 1024
#define N1 (3*Cc)      // 3072
#define N2 Cc          // 1024

typedef __attribute__((ext_vector_type(8))) short short8;
typedef __attribute__((ext_vector_type(4))) float float4v;

__device__ __forceinline__ unsigned short f2bf(float f) {
  unsigned int u = __builtin_bit_cast(unsigned int, f);
  u += 0x7FFFu + ((u >> 16) & 1u);   // RNE
  return (unsigned short)(u >> 16);
}

// ---------------- convert x (fp32 -> bf16), vectorized ----------------
__global__ __launch_bounds__(256) void k_cvt_x(const float* __restrict__ x,
                                               unsigned short* __restrict__ xb, int n4) {
  int i = blockIdx.x * 256 + threadIdx.x;
  if (i >= n4) return;
  float4 v = ((const float4*)x)[i];
  ushort4 o;
  o.x = f2bf(v.x); o.y = f2bf(v.y); o.z = f2bf(v.z); o.w = f2bf(v.w);
  ((ushort4*)xb)[i] = o;
}

// -------- transpose + convert weight [K,N] fp32 -> [N,K] bf16 ---------
__global__ __launch_bounds__(256) void k_cvt_wT(const float* __restrict__ w,
                                                unsigned short* __restrict__ wT,
                                                int K, int N) {
  __shared__ float tile[32][33];
  int n0 = blockIdx.x * 32, k0 = blockIdx.y * 32;
  int tx = threadIdx.x & 31, ty = threadIdx.x >> 5;   // 32 x 8
  for (int i = 0; i < 4; ++i)
    tile[ty + 8*i][tx] = w[(size_t)(k0 + ty + 8*i) * N + n0 + tx];
  __syncthreads();
  for (int i = 0; i < 4; ++i)
    wT[(size_t)(n0 + ty + 8*i) * K + k0 + tx] = f2bf(tile[tx][ty + 8*i]);
}

// ---------------- shared GEMM mainloop: C[128x128] tile ----------------
// A [M,K] bf16 row-major; BT [N,K] bf16 row-major (i.e. B transposed).
// 256 threads = 4 waves in 2x2; each wave computes 64x64 = 4x4 mfma tiles.
__device__ __forceinline__ void gemm_mainloop(const unsigned short* __restrict__ A,
                                              const unsigned short* __restrict__ BT,
                                              int m0, int n0,
                                              unsigned short* As, unsigned short* Bs,
                                              float4v acc[4][4]) {
  const int tid = threadIdx.x;
  const int w = tid >> 6, lane = tid & 63;
  const int ln = lane & 15, qd = lane >> 4;
  const int wm = w >> 1, wn = w & 1;
  const int c0 = tid, c1 = tid + 256;
  const int row0 = c0 >> 2, ko0 = (c0 & 3) * 8;
  const int row1 = c1 >> 2, ko1 = (c1 & 3) * 8;
  for (int kk = 0; kk < Kdim; kk += 32) {
    __syncthreads();
    {
      int4 a0 = *(const int4*)(A + (size_t)(m0 + row0) * Kdim + kk + ko0);
      int4 a1 = *(const int4*)(A + (size_t)(m0 + row1) * Kdim + kk + ko1);
      int4 b0 = *(const int4*)(BT + (size_t)(n0 + row0) * Kdim + kk + ko0);
      int4 b1 = *(const int4*)(BT + (size_t)(n0 + row1) * Kdim + kk + ko1);
      ((int4*)As)[c0] = a0; ((int4*)As)[c1] = a1;
      ((int4*)Bs)[c0] = b0; ((int4*)Bs)[c1] = b1;
    }
    __syncthreads();
    short8 af[4], bf[4];
    for (int i = 0; i < 4; ++i)
      af[i] = *(const short8*)(As + (wm*64 + i*16 + ln) * 32 + qd*8);
    for (int j = 0; j < 4; ++j)
      bf[j] = *(const short8*)(Bs + (wn*64 + j*16 + ln) * 32 + qd*8);
    for (int i = 0; i < 4; ++i)
      for (int j = 0; j < 4; ++j)
        acc[i][j] = __builtin_amdgcn_mfma_f32_16x16x32_bf16(af[i], bf[j], acc[i][j], 0, 0, 0);
  }
}

// ---- GEMM1: qkv = x @ Wqkv + bqkv, scatter to q/k/v [B,H,T,D] bf16 ----
// scale 1/sqrt(D)=0.125 folded into q.
__global__ __launch_bounds__(256) void k_gemm_qkv(const unsigned short* __restrict__ A,
                                                  const unsigned short* __restrict__ BT,
                                                  const float* __restrict__ bias,
                                                  unsigned short* __restrict__ qkv) {
  __shared__ alignas(16) unsigned short As[128*32];
  __shared__ alignas(16) unsigned short Bs[128*32];
  const int m0 = blockIdx.y * 128, n0 = blockIdx.x * 128;
  const float4v zero4 = {0.f, 0.f, 0.f, 0.f};
  float4v acc[4][4];
  for (int i = 0; i < 4; ++i) for (int j = 0; j < 4; ++j) acc[i][j] = zero4;
  gemm_mainloop(A, BT, m0, n0, As, Bs, acc);
  const int tid = threadIdx.x;
  const int w = tid >> 6, lane = tid & 63;
  const int ln = lane & 15, qd = lane >> 4;
  const int wm = w >> 1, wn = w & 1;
  for (int i = 0; i < 4; ++i) {
    int mbase = m0 + wm*64 + i*16 + qd*4;
    for (int j = 0; j < 4; ++j) {
      int ncol = n0 + wn*64 + j*16 + ln;
      float bv = bias[ncol];
      int s = ncol >> 10, rem = ncol & 1023;
      int h = rem >> 6, d = rem & 63;
      float scale = (s == 0) ? 0.125f : 1.0f;
      for (int r = 0; r < 4; ++r) {
        int m = mbase + r;
        int b = m >> 11, t = m & 2047;          // M = B*T, T=2048
        float val = (acc[i][j][r] + bv) * scale;
        qkv[((((size_t)s*Bc + b)*Hc + h)*Tc + t)*Dc + d] = f2bf(val);
      }
    }
  }
}

// ---- GEMM2: out = attn @ Wout + bout, fp32 output ----
__global__ __launch_bounds__(256) void k_gemm_out(const unsigned short* __restrict__ A,
                                                  const unsigned short* __restrict__ BT,
                                                  const float* __restrict__ bias,
                                                  float* __restrict__ out) {
  __shared__ alignas(16) unsigned short As[128*32];
  __shared__ alignas(16) unsigned short Bs[128*32];
  const int m0 = blockIdx.y * 128, n0 = blockIdx.x * 128;
  const float4v zero4 = {0.f, 0.f, 0.f, 0.f};
  float4v acc[4][4];
  for (int i = 0; i < 4; ++i) for (int j = 0; j < 4; ++j) acc[i][j] = zero4;
  gemm_mainloop(A, BT, m0, n0, As, Bs, acc);
  const int tid = threadIdx.x;
  const int w = tid >> 6, lane = tid & 63;
  const int ln = lane & 15, qd = lane >> 4;
  const int wm = w >> 1, wn = w & 1;
  for (int i = 0; i < 4; ++i) {
    int mbase = m0 + wm*64 + i*16 + qd*4;
    for (int j = 0; j < 4; ++j) {
      int ncol = n0 + wn*64 + j*16 + ln;
      float bv = bias[ncol];
      for (int r = 0; r < 4; ++r) {
        int m = mbase + r;
        out[(size_t)m * N2 + ncol] = acc[i][j][r] + bv;
      }
    }
  }
}

// ---- flash-style causal attention ----
// grid: (B*H) * (T/64); block 256 = 4 waves; wave w owns q rows [16w,16w+16).
// q,k,v are [B,H,T,D] bf16, q pre-scaled by 1/sqrt(D). out: [B,T,C] bf16.
__global__ __launch_bounds__(256) void k_attn(const unsigned short* __restrict__ qb,
                                              const unsigned short* __restrict__ kb,
                                              const unsigned short* __restrict__ vb,
                                              unsigned short* __restrict__ ob) {
  __shared__ alignas(16) unsigned short Ks[64*64];
  __shared__ alignas(16) unsigned short Vt[64*64];
  __shared__ alignas(16) unsigned short Ps[4][16*64];
  const int blk = blockIdx.x;
  const int qt = blk & 31;            // T/64 = 32 q-tiles
  const int bh = blk >> 5;            // 0..B*H-1
  const int tid = threadIdx.x;
  const int w = tid >> 6, lane = tid & 63;
  const int ln = lane & 15, qd = lane >> 4;
  const size_t base = (size_t)bh * Tc * Dc;
  const int q0 = qt * 64;
  const float L2E = 1.44269504f;
  const float4v zero4 = {0.f, 0.f, 0.f, 0.f};

  // Q fragments stay in registers for the whole block
  short8 qa0, qa1;
  {
    const unsigned short* qrow = qb + base + (size_t)(q0 + w*16 + ln) * Dc;
    qa0 = *(const short8*)(qrow + qd*8);
    qa1 = *(const short8*)(qrow + 32 + qd*8);
  }
  float4v o[4];
  for (int dt = 0; dt < 4; ++dt) o[dt] = zero4;
  float m_i[4], l_i[4];
  for (int r = 0; r < 4; ++r) { m_i[r] = -1e30f; l_i[r] = 0.f; }

  for (int kt = 0; kt <= qt; ++kt) {
    const int k0 = kt * 64;
    __syncthreads();   // protect Ks/Vt restage vs previous PV
    {
      const int4* src = (const int4*)(kb + base + (size_t)k0 * Dc);
      ((int4*)Ks)[tid]       = src[tid];
      ((int4*)Ks)[tid + 256] = src[tid + 256];
      const unsigned short* vsrc = vb + base + (size_t)k0 * Dc;
      for (int sb = 0; sb < 2; ++sb) {
        int c = tid + sb*256;
        int key = c >> 3, d0 = (c & 7) * 8;
        union { short8 v; unsigned short u[8]; } tmp;
        tmp.v = *(const short8*)(vsrc + key*Dc + d0);
        for (int j = 0; j < 8; ++j) Vt[(d0 + j)*64 + key] = tmp.u[j];
      }
    }
    __syncthreads();
    // S = Q K^T  (4 key sub-tiles of 16)
    float4v s[4];
    for (int ki = 0; ki < 4; ++ki) {
      s[ki] = zero4;
      const unsigned short* krow = Ks + (ki*16 + ln)*64;
      short8 kf0 = *(const short8*)(krow + qd*8);
      short8 kf1 = *(const short8*)(krow + 32 + qd*8);
      s[ki] = __builtin_amdgcn_mfma_f32_16x16x32_bf16(qa0, kf0, s[ki], 0, 0, 0);
      s[ki] = __builtin_amdgcn_mfma_f32_16x16x32_bf16(qa1, kf1, s[ki], 0, 0, 0);
    }
    if (kt == qt) {   // causal mask on the diagonal tile only
      for (int ki = 0; ki < 4; ++ki) {
        int key = k0 + ki*16 + ln;
        for (int r = 0; r < 4; ++r) {
          int q = q0 + w*16 + qd*4 + r;
          if (key > q) s[ki][r] = -1e30f;
        }
      }
    }
    // online softmax; row r lives on the 16 lanes of this quad -> shfl_xor reduce
    float mt[4];
    for (int r = 0; r < 4; ++r)
      mt[r] = fmaxf(fmaxf(s[0][r], s[1][r]), fmaxf(s[2][r], s[3][r]));
    for (int msk = 1; msk < 16; msk <<= 1)
      for (int r = 0; r < 4; ++r)
        mt[r] = fmaxf(mt[r], __shfl_xor(mt[r], msk));
    float al[4];
    for (int r = 0; r < 4; ++r) {
      float mn = fmaxf(m_i[r], mt[r]);
      al[r] = exp2f((m_i[r] - mn) * L2E);
      m_i[r] = mn;
    }
    for (int ki = 0; ki < 4; ++ki)
      for (int r = 0; r < 4; ++r)
        s[ki][r] = exp2f((s[ki][r] - m_i[r]) * L2E);
    float st[4];
    for (int r = 0; r < 4; ++r) st[r] = (s[0][r] + s[1][r]) + (s[2][r] + s[3][r]);
    for (int msk = 1; msk < 16; msk <<= 1)
      for (int r = 0; r < 4; ++r) st[r] += __shfl_xor(st[r], msk);
    for (int r = 0; r < 4; ++r) l_i[r] = l_i[r] * al[r] + st[r];
    for (int dt = 0; dt < 4; ++dt)
      for (int r = 0; r < 4; ++r) o[dt][r] *= al[r];
    // P: C/D layout -> LDS -> A layout (verified m120 recipe)
    unsigned short* pw = Ps[w];
    for (int ki = 0; ki < 4; ++ki)
      for (int r = 0; r < 4; ++r)
        pw[(qd*4 + r)*64 + ki*16 + ln] = f2bf(s[ki][r]);
    __syncthreads();
    short8 pa0 = *(const short8*)(pw + ln*64 + qd*8);
    short8 pa1 = *(const short8*)(pw + ln*64 + 32 + qd*8);
    for (int dt = 0; dt < 4; ++dt) {
      const unsigned short* vrow = Vt + (dt*16 + ln)*64;
      short8 vf0 = *(const short8*)(vrow + qd*8);
      short8 vf1 = *(const short8*)(vrow + 32 + qd*8);
      o[dt] = __builtin_amdgcn_mfma_f32_16x16x32_bf16(pa0, vf0, o[dt], 0, 0, 0);
      o[dt] = __builtin_amdgcn_mfma_f32_16x16x32_bf16(pa1, vf1, o[dt], 0, 0, 0);
    }
  }
  // epilogue: O /= l, write [B,T,C] bf16
  const int b = bh >> 4, h = bh & 15;
  for (int dt = 0; dt < 4; ++dt) {
    for (int r = 0; r < 4; ++r) {
      int t = q0 + w*16 + qd*4 + r;
      float val = o[dt][r] / l_i[r];
      ob[((size_t)(b*Tc + t))*Cc + h*Dc + dt*16 + ln] = f2bf(val);
    }
  }
}

extern "C" void kernel_launch(void* const* d_in, const int* in_sizes, int n_in,
                              void* d_out, int out_size, void* d_ws, size_t ws_size,
                              hipStream_t stream) {
  const float* x    = (const float*)d_in[0];
  const float* Wqkv = (const float*)d_in[1];
  const float* bqkv = (const float*)d_in[2];
  const float* Wout = (const float*)d_in[3];
  const float* bout = (const float*)d_in[4];
  float* out = (float*)d_out;

  char* ws = (char*)d_ws;
  // layout (bytes): xb 8388608 | wqkvT 6291456 | woutT 2097152 | qkv 25165824
  unsigned short* xb    = (unsigned short*)ws;                    // also reused as attn_out
  unsigned short* wqkvT = (unsigned short*)(ws + 8388608);
  unsigned short* woutT = (unsigned short*)(ws + 14680064);
  unsigned short* qkvb  = (unsigned short*)(ws + 16777216);

  k_cvt_x<<<(Mtot*Kdim/4 + 255)/256, 256, 0, stream>>>(x, xb, Mtot*Kdim/4);
  k_cvt_wT<<<dim3(N1/32, Kdim/32), 256, 0, stream>>>(Wqkv, wqkvT, Kdim, N1);
  k_cvt_wT<<<dim3(N2/32, Kdim/32), 256, 0, stream>>>(Wout, woutT, Kdim, N2);
  k_gemm_qkv<<<dim3(N1/128, Mtot/128), 256, 0, stream>>>(xb, wqkvT, bqkv, qkvb);
  k_attn<<<Bc*Hc*(Tc/64), 256, 0, stream>>>(qkvb, qkvb + (size_t)Bc*Hc*Tc*Dc,
                                            qkvb + (size_t)2*Bc*Hc*Tc*Dc, xb);
  k_gemm_out<<<dim3(N2/128, Mtot/128), 256, 0, stream>>>(xb, woutT, bout, out);
}

// Round 2
// 229.056 us; speedup vs baseline: 1.5601x; 1.5601x over previous
//
#include <hip/hip_runtime.h>

#define Bc 2
#define Tc 2048
#define Cc 1024
#define Hc 16
#define Dc 64
#define Mtot (Bc*Tc)   // 4096
#define Kdim Cc        // 1024
#define N1 (3*Cc)      // 3072
#define N2 Cc          // 1024

typedef __attribute__((ext_vector_type(8))) short short8;
typedef __attribute__((ext_vector_type(4))) float float4v;

__device__ __forceinline__ unsigned short f2bf(float f) {
  unsigned int u = __builtin_bit_cast(unsigned int, f);
  u += 0x7FFFu + ((u >> 16) & 1u);   // RNE
  return (unsigned short)(u >> 16);
}

// async global->LDS, 16B per lane. LDS dest must be wave-uniform base + lane*16.
__device__ __forceinline__ void gl2lds16(const unsigned short* g, unsigned short* l) {
  __builtin_amdgcn_global_load_lds((const __attribute__((address_space(1))) void*)g,
                                   (__attribute__((address_space(3))) void*)l, 16, 0, 0);
}

// ---------------- convert x (fp32 -> bf16), vectorized ----------------
__global__ __launch_bounds__(256) void k_cvt_x(const float* __restrict__ x,
                                               unsigned short* __restrict__ xb, int n4) {
  int i = blockIdx.x * 256 + threadIdx.x;
  if (i >= n4) return;
  float4 v = ((const float4*)x)[i];
  ushort4 o;
  o.x = f2bf(v.x); o.y = f2bf(v.y); o.z = f2bf(v.z); o.w = f2bf(v.w);
  ((ushort4*)xb)[i] = o;
}

// -------- transpose + convert weight [K,N] fp32 -> [N,K] bf16 ---------
__global__ __launch_bounds__(256) void k_cvt_wT(const float* __restrict__ w,
                                                unsigned short* __restrict__ wT,
                                                int K, int N) {
  __shared__ float tile[32][33];
  int n0 = blockIdx.x * 32, k0 = blockIdx.y * 32;
  int tx = threadIdx.x & 31, ty = threadIdx.x >> 5;   // 32 x 8
  for (int i = 0; i < 4; ++i)
    tile[ty + 8*i][tx] = w[(size_t)(k0 + ty + 8*i) * N + n0 + tx];
  __syncthreads();
  for (int i = 0; i < 4; ++i)
    wT[(size_t)(n0 + ty + 8*i) * K + k0 + tx] = f2bf(tile[tx][ty + 8*i]);
}

// ---------------- shared GEMM mainloop: C[128x128] tile ----------------
// A [M,K] bf16 row-major; BT [N,K] bf16 row-major. global_load_lds staging (m97).
__device__ __forceinline__ void gemm_mainloop(const unsigned short* __restrict__ A,
                                              const unsigned short* __restrict__ BT,
                                              int m0, int n0,
                                              unsigned short* As, unsigned short* Bs,
                                              float4v acc[4][4]) {
  const int tid = threadIdx.x;
  const int w = tid >> 6, lane = tid & 63;
  const int ln = lane & 15, qd = lane >> 4;
  const int wm = w >> 1, wn = w & 1;
  const int c0 = tid, c1 = tid + 256;
  const int row0 = c0 >> 2, ko0 = (c0 & 3) * 8;
  const int row1 = c1 >> 2, ko1 = (c1 & 3) * 8;
  for (int kk = 0; kk < Kdim; kk += 32) {
    __syncthreads();
    gl2lds16(A  + (size_t)(m0 + row0) * Kdim + kk + ko0, As + c0 * 8);
    gl2lds16(A  + (size_t)(m0 + row1) * Kdim + kk + ko1, As + c1 * 8);
    gl2lds16(BT + (size_t)(n0 + row0) * Kdim + kk + ko0, Bs + c0 * 8);
    gl2lds16(BT + (size_t)(n0 + row1) * Kdim + kk + ko1, Bs + c1 * 8);
    __syncthreads();
    short8 af[4], bf[4];
    for (int i = 0; i < 4; ++i)
      af[i] = *(const short8*)(As + (wm*64 + i*16 + ln) * 32 + qd*8);
    for (int j = 0; j < 4; ++j)
      bf[j] = *(const short8*)(Bs + (wn*64 + j*16 + ln) * 32 + qd*8);
    for (int i = 0; i < 4; ++i)
      for (int j = 0; j < 4; ++j)
        acc[i][j] = __builtin_amdgcn_mfma_f32_16x16x32_bf16(af[i], bf[j], acc[i][j], 0, 0, 0);
  }
}

// ---- GEMM1: qkv = x @ Wqkv + bqkv; q,k -> [B,H,T,D], v -> [B,H,D,T] (transposed) ----
// scale 1/sqrt(D)=0.125 folded into q (and its bias).
__global__ __launch_bounds__(256) void k_gemm_qkv(const unsigned short* __restrict__ A,
                                                  const unsigned short* __restrict__ BT,
                                                  const float* __restrict__ bias,
                                                  unsigned short* __restrict__ qkv) {
  __shared__ alignas(16) unsigned short As[128*32];
  __shared__ alignas(16) unsigned short Bs[128*32];
  const int m0 = blockIdx.y * 128, n0 = blockIdx.x * 128;
  const float4v zero4 = {0.f, 0.f, 0.f, 0.f};
  float4v acc[4][4];
  for (int i = 0; i < 4; ++i) for (int j = 0; j < 4; ++j) acc[i][j] = zero4;
  gemm_mainloop(A, BT, m0, n0, As, Bs, acc);
  const int tid = threadIdx.x;
  const int w = tid >> 6, lane = tid & 63;
  const int ln = lane & 15, qd = lane >> 4;
  const int wm = w >> 1, wn = w & 1;
  for (int i = 0; i < 4; ++i) {
    int mbase = m0 + wm*64 + i*16 + qd*4;
    for (int j = 0; j < 4; ++j) {
      int ncol = n0 + wn*64 + j*16 + ln;
      float bv = bias[ncol];
      int s = ncol >> 10, rem = ncol & 1023;
      int h = rem >> 6, d = rem & 63;
      float scale = (s == 0) ? 0.125f : 1.0f;
      for (int r = 0; r < 4; ++r) {
        int m = mbase + r;
        int b = m >> 11, t = m & 2047;          // M = B*T, T=2048
        float val = (acc[i][j][r] + bv) * scale;
        size_t idx = (s < 2)
          ? ((((size_t)s*Bc + b)*Hc + h)*Tc + t)*Dc + d
          : (size_t)2*Bc*Hc*Tc*Dc + (((size_t)b*Hc + h)*Dc + d)*Tc + t;
        qkv[idx] = f2bf(val);
      }
    }
  }
}

// ---- GEMM2: out = attn @ Wout + bout, fp32 output ----
__global__ __launch_bounds__(256) void k_gemm_out(const unsigned short* __restrict__ A,
                                                  const unsigned short* __restrict__ BT,
                                                  const float* __restrict__ bias,
                                                  float* __restrict__ out) {
  __shared__ alignas(16) unsigned short As[128*32];
  __shared__ alignas(16) unsigned short Bs[128*32];
  const int m0 = blockIdx.y * 128, n0 = blockIdx.x * 128;
  const float4v zero4 = {0.f, 0.f, 0.f, 0.f};
  float4v acc[4][4];
  for (int i = 0; i < 4; ++i) for (int j = 0; j < 4; ++j) acc[i][j] = zero4;
  gemm_mainloop(A, BT, m0, n0, As, Bs, acc);
  const int tid = threadIdx.x;
  const int w = tid >> 6, lane = tid & 63;
  const int ln = lane & 15, qd = lane >> 4;
  const int wm = w >> 1, wn = w & 1;
  for (int i = 0; i < 4; ++i) {
    int mbase = m0 + wm*64 + i*16 + qd*4;
    for (int j = 0; j < 4; ++j) {
      int ncol = n0 + wn*64 + j*16 + ln;
      float bv = bias[ncol];
      for (int r = 0; r < 4; ++r) {
        int m = mbase + r;
        out[(size_t)m * N2 + ncol] = acc[i][j][r] + bv;
      }
    }
  }
}

// ---- flash-style causal attention, S^T orientation ----
// grid: (B*H)*16; block = 4 waves. Block handles q-tiles {p, 31-p} -> 33 k-tile steps.
// Wave w owns q rows [qt*64+16w, +16); lane ln = one q row. All softmax state scalar/lane.
// q,k: [B,H,T,D] (q pre-scaled); v: [B,H,D,T]. out: [B,T,C] bf16.
__global__ __launch_bounds__(256) void k_attn(const unsigned short* __restrict__ qb,
                                              const unsigned short* __restrict__ kb,
                                              const unsigned short* __restrict__ vT,
                                              unsigned short* __restrict__ ob) {
  __shared__ alignas(16) unsigned short Ks[64*72];     // [key][d], stride 72
  __shared__ alignas(16) unsigned short Vt[64*72];     // [d][key], stride 72
  __shared__ alignas(16) unsigned short Ps[4][16*72];  // per-wave [q][key], stride 72
  const int blk = blockIdx.x;
  const int pp = blk & 15, bh = blk >> 4;
  const int tid = threadIdx.x;
  const int w = tid >> 6, lane = tid & 63;
  const int ln = lane & 15, qd = lane >> 4;
  const size_t base = (size_t)bh * Tc * Dc;            // same size for K and V^T bases
  const int b = bh >> 4, h = bh & 15;
  const int srow = tid >> 3, scol = (tid & 7) * 8;     // staging: 32 rows x 8 int4
  const float L2E = 1.44269504f;
  const float4v zero4 = {0.f, 0.f, 0.f, 0.f};
  unsigned short* pw = Ps[w];

  for (int pass = 0; pass < 2; ++pass) {
    const int qt = pass ? (31 - pp) : pp;
    const int q0 = qt * 64;
    const int myq = q0 + w*16 + ln;
    const unsigned short* qrow = qb + base + (size_t)myq * Dc;
    short8 qa0 = *(const short8*)(qrow + qd*8);
    short8 qa1 = *(const short8*)(qrow + 32 + qd*8);
    float4v o[4];
    for (int dt = 0; dt < 4; ++dt) o[dt] = zero4;
    float m_i = -1e30f, l_i = 0.f;

    for (int kt = 0; kt <= qt; ++kt) {
      const int k0 = kt * 64;
      __syncthreads();   // previous tile's LDS reads done before restage
      *(int4*)(Ks + srow*72 + scol)      = *(const int4*)(kb + base + (size_t)(k0 + srow)*Dc + scol);
      *(int4*)(Ks + (srow+32)*72 + scol) = *(const int4*)(kb + base + (size_t)(k0 + srow+32)*Dc + scol);
      *(int4*)(Vt + srow*72 + scol)      = *(const int4*)(vT + base + (size_t)srow*Tc + k0 + scol);
      *(int4*)(Vt + (srow+32)*72 + scol) = *(const int4*)(vT + base + (size_t)(srow+32)*Tc + k0 + scol);
      __syncthreads();

      // S^T = K·Q^T: lane holds q=myq (col), keys ki*16+qd*4+r (rows)
      float4v s[4];
      for (int ki = 0; ki < 4; ++ki) {
        s[ki] = zero4;
        const unsigned short* kr = Ks + (ki*16 + ln)*72;
        short8 kf0 = *(const short8*)(kr + qd*8);
        short8 kf1 = *(const short8*)(kr + 32 + qd*8);
        s[ki] = __builtin_amdgcn_mfma_f32_16x16x32_bf16(kf0, qa0, s[ki], 0, 0, 0);
        s[ki] = __builtin_amdgcn_mfma_f32_16x16x32_bf16(kf1, qa1, s[ki], 0, 0, 0);
      }
      if (kt == qt) {   // causal mask on diagonal tile
        for (int ki = 0; ki < 4; ++ki) {
          int key = k0 + ki*16 + qd*4;
          for (int r = 0; r < 4; ++r)
            if (key + r > myq) s[ki][r] = -1e30f;
        }
      }
      // online softmax: per-lane scalar state; reduce over qd (lanes ln+16*qd)
      float mt = -1e30f;
      for (int ki = 0; ki < 4; ++ki)
        for (int r = 0; r < 4; ++r) mt = fmaxf(mt, s[ki][r]);
      mt = fmaxf(mt, __shfl_xor(mt, 16));
      mt = fmaxf(mt, __shfl_xor(mt, 32));
      float mn = fmaxf(m_i, mt);
      float al = exp2f((m_i - mn) * L2E);
      m_i = mn;
      float st = 0.f;
      for (int ki = 0; ki < 4; ++ki)
        for (int r = 0; r < 4; ++r) {
          s[ki][r] = exp2f((s[ki][r] - mn) * L2E);
          st += s[ki][r];
        }
      st += __shfl_xor(st, 16);
      st += __shfl_xor(st, 32);
      l_i = l_i * al + st;
      for (int dt = 0; dt < 4; ++dt)
        for (int r = 0; r < 4; ++r) o[dt][r] *= al;

      // P store: lane's 4 consecutive keys of row q=ln -> one 8B write per ki
      for (int ki = 0; ki < 4; ++ki) {
        ushort4 p4;
        p4.x = f2bf(s[ki][0]); p4.y = f2bf(s[ki][1]);
        p4.z = f2bf(s[ki][2]); p4.w = f2bf(s[ki][3]);
        *(ushort4*)(pw + ln*72 + ki*16 + qd*4) = p4;
      }
      // O^T += V^T · P^T  (per-wave P buffer: no barrier, DS in-order per wave)
      short8 pb0 = *(const short8*)(pw + ln*72 + qd*8);
      short8 pb1 = *(const short8*)(pw + ln*72 + 32 + qd*8);
      for (int dt = 0; dt < 4; ++dt) {
        const unsigned short* vr = Vt + (dt*16 + ln)*72;
        short8 va0 = *(const short8*)(vr + qd*8);
        short8 va1 = *(const short8*)(vr + 32 + qd*8);
        o[dt] = __builtin_amdgcn_mfma_f32_16x16x32_bf16(va0, pb0, o[dt], 0, 0, 0);
        o[dt] = __builtin_amdgcn_mfma_f32_16x16x32_bf16(va1, pb1, o[dt], 0, 0, 0);
      }
    }
    // epilogue: lane writes 4 consecutive d per dt as one 8B store
    float inv = 1.0f / l_i;
    for (int dt = 0; dt < 4; ++dt) {
      ushort4 ov;
      ov.x = f2bf(o[dt][0] * inv); ov.y = f2bf(o[dt][1] * inv);
      ov.z = f2bf(o[dt][2] * inv); ov.w = f2bf(o[dt][3] * inv);
      *(ushort4*)(ob + (size_t)(b*Tc + myq)*Cc + h*Dc + dt*16 + qd*4) = ov;
    }
  }
}

extern "C" void kernel_launch(void* const* d_in, const int* in_sizes, int n_in,
                              void* d_out, int out_size, void* d_ws, size_t ws_size,
                              hipStream_t stream) {
  const float* x    = (const float*)d_in[0];
  const float* Wqkv = (const float*)d_in[1];
  const float* bqkv = (const float*)d_in[2];
  const float* Wout = (const float*)d_in[3];
  const float* bout = (const float*)d_in[4];
  float* out = (float*)d_out;

  char* ws = (char*)d_ws;
  unsigned short* xb    = (unsigned short*)ws;                    // reused as attn_out
  unsigned short* wqkvT = (unsigned short*)(ws + 8388608);
  unsigned short* woutT = (unsigned short*)(ws + 14680064);
  unsigned short* qkvb  = (unsigned short*)(ws + 16777216);

  k_cvt_x<<<(Mtot*Kdim/4 + 255)/256, 256, 0, stream>>>(x, xb, Mtot*Kdim/4);
  k_cvt_wT<<<dim3(N1/32, Kdim/32), 256, 0, stream>>>(Wqkv, wqkvT, Kdim, N1);
  k_cvt_wT<<<dim3(N2/32, Kdim/32), 256, 0, stream>>>(Wout, woutT, Kdim, N2);
  k_gemm_qkv<<<dim3(N1/128, Mtot/128), 256, 0, stream>>>(xb, wqkvT, bqkv, qkvb);
  k_attn<<<Bc*Hc*16, 256, 0, stream>>>(qkvb, qkvb + (size_t)Bc*Hc*Tc*Dc,
                                       qkvb + (size_t)2*Bc*Hc*Tc*Dc, xb);
  k_gemm_out<<<dim3(N2/128, Mtot/128), 256, 0, stream>>>(xb, woutT, bout, out);
}